// Round 7
// baseline (2358.593 us; speedup 1.0000x reference)
//
#include <hip/hip_runtime.h>

// Problem constants (match reference)
constexpr int NN   = 50000;          // nodes
constexpr int NE   = 800000;         // edges before self loops
constexpr int NHD  = 4;              // heads
constexpr int CC   = 32;             // channels per head
constexpr int HCC  = 128;            // NHD*CC
constexpr int NL   = 3;              // layers
constexpr int NG   = 128;            // graphs
constexpr int NOUT = 10;             // out channels
constexpr float BN_EPS = 1e-5f;

constexpr int XS = 133;              // LDS x-row stride
constexpr int YS = 33;               // LDS y-row stride
constexpr int DB = 32;               // dst nodes per k_agg block
constexpr int AS = 130;              // LDS acc row stride (2-way bank alias = free)

// fp32 -> bf16 (round-to-nearest-even), packed pair helpers
__device__ inline unsigned f2bf_pack(float a, float b) {
    unsigned ua = __float_as_uint(a); ua += 0x7FFFu + ((ua >> 16) & 1u);
    unsigned ub = __float_as_uint(b); ub += 0x7FFFu + ((ub >> 16) & 1u);
    return (ua >> 16) | (ub & 0xFFFF0000u);
}
__device__ inline float bf_lo(unsigned p) { return __uint_as_float(p << 16); }
__device__ inline float bf_hi(unsigned p) { return __uint_as_float(p & 0xFFFF0000u); }

// -------------------------------------- embed gather + BN stats for layer 0
__global__ __launch_bounds__(256) void k_embed_stats(const int* __restrict__ idx,
                                                     const float* __restrict__ embed,
                                                     float* __restrict__ x,
                                                     float* __restrict__ stats) {
    int i0 = blockIdx.x * 256 + threadIdx.x;
    int stride = gridDim.x * 256;                 // multiple of 128
    float s = 0.f, q = 0.f;
    for (int i = i0; i < NN * HCC; i += stride) {
        float v = embed[idx[i >> 7] * HCC + (i & 127)];
        x[i] = v; s += v; q += v * v;
    }
    __shared__ float ssum[256], ssq[256];
    ssum[threadIdx.x] = s; ssq[threadIdx.x] = q;
    __syncthreads();
    if (threadIdx.x < HCC) {
        atomicAdd(&stats[threadIdx.x],       ssum[threadIdx.x] + ssum[threadIdx.x + HCC]);
        atomicAdd(&stats[HCC + threadIdx.x], ssq[threadIdx.x]  + ssq[threadIdx.x + HCC]);
    }
}

// ------------------------------------------------------------ CSR build: degree
__global__ __launch_bounds__(256) void k_hist(const int* __restrict__ ei,
                                              int* __restrict__ deg) {
    int e = blockIdx.x * 256 + threadIdx.x;
    if (e >= NE) return;
    atomicAdd(&deg[ei[NE + e]], 1);
}

// chunked single-block exclusive scan
__global__ __launch_bounds__(1024) void k_scan(const int* __restrict__ deg,
                                               int* __restrict__ rowptr) {
    __shared__ int sh[1024];
    int tid = threadIdx.x;
    const int CH = (NN + 1023) / 1024;            // 49
    int st = tid * CH, en = min(st + CH, NN);
    int sum = 0;
    for (int i = st; i < en; i++) sum += deg[i];
    sh[tid] = sum;
    __syncthreads();
    for (int off = 1; off < 1024; off <<= 1) {
        int v = (tid >= off) ? sh[tid - off] : 0;
        __syncthreads();
        sh[tid] += v;
        __syncthreads();
    }
    int base = sh[tid] - sum;                     // exclusive prefix of chunk
    for (int i = st; i < en; i++) { rowptr[i] = base; base += deg[i]; }
}

// scatter edges by dst into packed (src,dst) records.
// Mutates rowptr: afterwards rowptr[d] == end(d).
__global__ __launch_bounds__(256) void k_scatter(const int* __restrict__ ei,
                                                 int* __restrict__ rowptr,
                                                 int2* __restrict__ epair) {
    int e = blockIdx.x * 256 + threadIdx.x;
    if (e >= NE) return;
    int d = ei[NE + e];
    int pos = atomicAdd(&rowptr[d], 1);
    epair[pos] = make_int2(ei[e], d);
}

// ---------- fused BNfin + BN-apply + Linear(128->32)+ReLU + GATw(32->128) + att
__global__ __launch_bounds__(256) void k_fused(const float* __restrict__ x,
                                               const float* __restrict__ stats,
                                               const float* __restrict__ gamma,
                                               const float* __restrict__ beta,
                                               const float* __restrict__ W1, // [32,128]
                                               const float* __restrict__ b1, // [32]
                                               const float* __restrict__ W2, // [128,32]
                                               const float* __restrict__ aS, // [4,32]
                                               const float* __restrict__ aD, // [4,32]
                                               unsigned* __restrict__ h,     // [N,64] packed
                                               float* __restrict__ asrc,     // [N,4]
                                               float* __restrict__ adst) {   // [N,4]
    __shared__ float xb[64 * XS];
    __shared__ float yt[64 * YS];
    __shared__ float w1[32 * 128];
    __shared__ float w2[128 * 32];
    __shared__ float attS[128], attD[128], ssl[256];
    int tid = threadIdx.x;
    int node0 = blockIdx.x * 64;
    int nNodes = min(64, NN - node0);

    for (int i = tid; i < 4096; i += 256) { w1[i] = W1[i]; w2[i] = W2[i]; }
    if (tid < 128) {
        attS[tid] = aS[tid]; attD[tid] = aD[tid];
        float mean = stats[tid] * (1.0f / NN);
        float var  = stats[HCC + tid] * (1.0f / NN) - mean * mean;
        float sc   = gamma[tid] * rsqrtf(var + BN_EPS);
        ssl[tid]       = sc;
        ssl[HCC + tid] = beta[tid] - mean * sc;
    }
    __syncthreads();   // ssl read cross-wave below

    for (int f4 = tid; f4 < nNodes * 32; f4 += 256) {
        int f = f4 * 4; int n = f >> 7; int c = f & 127;
        float4 xv = *(const float4*)(x + (size_t)(node0 + n) * HCC + c);
        float* dst = &xb[n * XS + c];
        dst[0] = xv.x * ssl[c]     + ssl[HCC + c];
        dst[1] = xv.y * ssl[c + 1] + ssl[HCC + c + 1];
        dst[2] = xv.z * ssl[c + 2] + ssl[HCC + c + 2];
        dst[3] = xv.w * ssl[c + 3] + ssl[HCC + c + 3];
    }
    __syncthreads();

    int lane = tid & 63, wv = tid >> 6;
    int n = lane;

    // ---- stage 1: y[n][j0..j0+7]
    {
        int j0 = wv * 8;
        float acc[8];
#pragma unroll
        for (int k = 0; k < 8; k++) acc[k] = b1[j0 + k];
        if (n < nNodes) {
            for (int cb = 0; cb < 128; cb += 4) {
                float xv0 = xb[n * XS + cb],     xv1 = xb[n * XS + cb + 1];
                float xv2 = xb[n * XS + cb + 2], xv3 = xb[n * XS + cb + 3];
#pragma unroll
                for (int k = 0; k < 8; k++) {
                    float4 w = *(const float4*)&w1[(j0 + k) * 128 + cb];
                    acc[k] += xv0 * w.x + xv1 * w.y + xv2 * w.z + xv3 * w.w;
                }
            }
#pragma unroll
            for (int k = 0; k < 8; k++) yt[n * YS + j0 + k] = fmaxf(acc[k], 0.f);
        }
    }
    __syncthreads();

    // ---- stage 2: h[n][k0..k0+31] (bf16), head hd = wv, + attention dots
    if (n < nNodes) {
        int k0 = wv * 32, hd = wv;
        float yreg[32];
#pragma unroll
        for (int j = 0; j < 32; j++) yreg[j] = yt[n * YS + j];
        float sa = 0.f, da = 0.f;
        unsigned* hrow = h + (size_t)(node0 + n) * 64;
        for (int kb = 0; kb < 32; kb += 8) {
            float acck[8];
#pragma unroll
            for (int kk = 0; kk < 8; kk++) acck[kk] = 0.f;
#pragma unroll
            for (int j = 0; j < 32; j += 4) {
#pragma unroll
                for (int kk = 0; kk < 8; kk++) {
                    float4 w = *(const float4*)&w2[(k0 + kb + kk) * 32 + j];
                    acck[kk] += yreg[j] * w.x + yreg[j + 1] * w.y +
                                yreg[j + 2] * w.z + yreg[j + 3] * w.w;
                }
            }
#pragma unroll
            for (int kk = 0; kk < 8; kk++) {
                sa += acck[kk] * attS[hd * 32 + kb + kk];
                da += acck[kk] * attD[hd * 32 + kb + kk];
            }
            uint4 pk;
            pk.x = f2bf_pack(acck[0], acck[1]);
            pk.y = f2bf_pack(acck[2], acck[3]);
            pk.z = f2bf_pack(acck[4], acck[5]);
            pk.w = f2bf_pack(acck[6], acck[7]);
            *(uint4*)(hrow + ((k0 + kb) >> 1)) = pk;
        }
        asrc[(node0 + n) * 4 + hd] = sa;
        adst[(node0 + n) * 4 + hd] = da;
    }
}

// -------- edge-parallel gather-aggregate with LDS accumulation.
// Block owns dst range [d0, d0+32); processes its contiguous CSR edge range
// one edge per wave per step (4-deep unroll). Lane L owns channels 2L, 2L+1.
__global__ __launch_bounds__(256) void k_agg(const int* __restrict__ rowptr,
                                             const int2* __restrict__ epair,
                                             const float* __restrict__ asrc,
                                             const float* __restrict__ adst,
                                             const unsigned* __restrict__ h, // [N,64]
                                             const float* __restrict__ gat_b,
                                             float* __restrict__ xo,
                                             float* __restrict__ stats,
                                             int do_stats) {
    __shared__ float acc[DB * AS];        // [dd][L] = ch 2L ; [dd][64+L] = ch 2L+1
    __shared__ float wsumL[DB * NHD];
    int tid = threadIdx.x, lane = tid & 63, wv = tid >> 6;
    int hd = lane >> 4;
    int d0 = blockIdx.x * DB;

    for (int i = tid; i < DB * AS; i += 256) acc[i] = 0.f;
    for (int i = tid; i < DB * NHD; i += 256) wsumL[i] = 0.f;
    __syncthreads();

    int eBegin = d0 ? rowptr[d0 - 1] : 0;
    int lastd = min(d0 + DB - 1, NN - 1);
    int eEnd = rowptr[lastd];

    for (int j0 = eBegin + wv * 4; j0 < eEnd; j0 += 16) {
        int jc[4];
#pragma unroll
        for (int t = 0; t < 4; t++) {
            int jt = j0 + t;
            jc[t] = jt < eEnd ? jt : eEnd - 1;      // clamp; wt forced 0 below
        }
        int2 pr[4];
#pragma unroll
        for (int t = 0; t < 4; t++) pr[t] = epair[jc[t]];
        unsigned hp[4];
#pragma unroll
        for (int t = 0; t < 4; t++) hp[t] = h[pr[t].x * 64 + lane];
        float wt[4];
#pragma unroll
        for (int t = 0; t < 4; t++) {
            float l = asrc[pr[t].x * 4 + hd] + adst[pr[t].y * 4 + hd];
            l = l > 0.f ? l : 0.2f * l;
            float w = __expf(l);
            wt[t] = (j0 + t < eEnd) ? w : 0.f;
        }
#pragma unroll
        for (int t = 0; t < 4; t++) {
            int dd = pr[t].y - d0;
            atomicAdd(&acc[dd * AS + lane],      wt[t] * bf_lo(hp[t]));
            atomicAdd(&acc[dd * AS + 64 + lane], wt[t] * bf_hi(hp[t]));
            if ((lane & 15) == 0) atomicAdd(&wsumL[dd * NHD + hd], wt[t]);
        }
    }
    __syncthreads();

    // epilogue: self loop + normalize + bias + store; 8 nodes per wave
    int c0 = lane * 2;
    float bs0 = gat_b[c0], bs1 = gat_b[c0 + 1];
    float S0 = 0, S1 = 0, Q0 = 0, Q1 = 0;
    for (int nn = 0; nn < DB / 4; nn++) {
        int dd = wv * (DB / 4) + nn;
        int d = d0 + dd;
        if (d >= NN) break;
        float adv = adst[d * 4 + hd];
        float sl = asrc[d * 4 + hd] + adv; sl = sl > 0.f ? sl : 0.2f * sl;
        float w = __expf(sl);
        unsigned hp = h[d * 64 + lane];
        float a0 = acc[dd * AS + lane]      + w * bf_lo(hp);
        float a1 = acc[dd * AS + 64 + lane] + w * bf_hi(hp);
        float ws = wsumL[dd * NHD + hd] + w;
        float inv = 1.0f / (ws + 1e-16f);
        float o0 = a0 * inv + bs0, o1 = a1 * inv + bs1;
        *(float2*)(xo + (size_t)d * HCC + c0) = make_float2(o0, o1);
        S0 += o0; S1 += o1; Q0 += o0 * o0; Q1 += o1 * o1;
    }
    if (!do_stats) return;
    __shared__ float redS[512], redQ[512];
    redS[wv * 128 + c0] = S0; redS[wv * 128 + c0 + 1] = S1;
    redQ[wv * 128 + c0] = Q0; redQ[wv * 128 + c0 + 1] = Q1;
    __syncthreads();
    if (tid < 128) {
        float v = redS[tid] + redS[128 + tid] + redS[256 + tid] + redS[384 + tid];
        atomicAdd(&stats[tid], v);
    } else if (tid < 256) {
        int c = tid - 128;
        float v = redQ[c] + redQ[128 + c] + redQ[256 + c] + redQ[384 + c];
        atomicAdd(&stats[128 + c], v);
    }
}

// ------------------------------------------------------- readout + graph pool
__global__ __launch_bounds__(256) void k_readout(const float* __restrict__ x,
                                                 const int* __restrict__ batch,
                                                 const float* __restrict__ W,  // [10,128]
                                                 const float* __restrict__ bb, // [10]
                                                 float* __restrict__ out) {    // [128,10]
    int i = blockIdx.x * 256 + threadIdx.x;
    if (i >= NN * NOUT) return;
    int n = i / NOUT, j = i - n * NOUT;
    const float* xr = x + (size_t)n * HCC;
    const float* wr = W + j * HCC;
    float acc = bb[j];
#pragma unroll
    for (int c = 0; c < HCC; c += 4) {
        float4 xv = *(const float4*)(xr + c);
        float4 wv = *(const float4*)(wr + c);
        acc += xv.x * wv.x + xv.y * wv.y + xv.z * wv.z + xv.w * wv.w;
    }
    atomicAdd(&out[batch[n] * NOUT + j], acc);
}

extern "C" void kernel_launch(void* const* d_in, const int* in_sizes, int n_in,
                              void* d_out, int out_size, void* d_ws, size_t ws_size,
                              hipStream_t stream) {
    const int*   x_idx = (const int*)d_in[0];
    const int*   ei    = (const int*)d_in[1];
    const int*   batch = (const int*)d_in[2];
    const float* embed = (const float*)d_in[3];
    const float* bn_g  = (const float*)d_in[4];
    const float* bn_b  = (const float*)d_in[5];
    const float* lin_W = (const float*)d_in[6];
    const float* lin_b = (const float*)d_in[7];
    const float* gat_W = (const float*)d_in[8];
    const float* att_s = (const float*)d_in[9];
    const float* att_d = (const float*)d_in[10];
    const float* gat_b = (const float*)d_in[11];
    const float* ro_W  = (const float*)d_in[12];
    const float* ro_b  = (const float*)d_in[13];
    float* out = (float*)d_out;

    // workspace layout
    float*    x     = (float*)d_ws;                        // [N,128] fp32
    unsigned* h     = (unsigned*)(x + (size_t)NN * HCC);   // [N,64] packed bf16
    float*    asrc  = (float*)(h + (size_t)NN * 64);       // [N,4]
    float*    adst  = asrc + (size_t)NN * NHD;             // [N,4]
    float*    stats = adst + (size_t)NN * NHD;             // [4][256]
    int*      deg    = (int*)(stats + 4 * 2 * HCC);        // [N]
    int*      rowptr = deg + NN;                           // [N]
    int2*     epair  = (int2*)(rowptr + NN);               // [E] (src,dst)

    hipMemsetAsync(stats, 0, 4 * 2 * HCC * sizeof(float), stream);
    hipMemsetAsync(deg, 0, NN * sizeof(int), stream);

    k_embed_stats<<<512, 256, 0, stream>>>(x_idx, embed, x, stats);

    // CSR build (graph is static across layers)
    k_hist<<<(NE + 255) / 256, 256, 0, stream>>>(ei, deg);
    k_scan<<<1, 1024, 0, stream>>>(deg, rowptr);
    k_scatter<<<(NE + 255) / 256, 256, 0, stream>>>(ei, rowptr, epair);

    for (int l = 0; l < NL; ++l) {
        k_fused<<<(NN + 63) / 64, 256, 0, stream>>>(x, stats + l * 2 * HCC,
                                                    bn_g + l * HCC, bn_b + l * HCC,
                                                    lin_W + l * CC * HCC, lin_b + l * CC,
                                                    gat_W + l * HCC * CC,
                                                    att_s + l * NHD * CC,
                                                    att_d + l * NHD * CC,
                                                    h, asrc, adst);
        k_agg<<<(NN + DB - 1) / DB, 256, 0, stream>>>(rowptr, epair, asrc, adst, h,
                                                      gat_b + l * HCC, x,
                                                      stats + (l + 1) * 2 * HCC,
                                                      (l < NL - 1) ? 1 : 0);
    }

    hipMemsetAsync(out, 0, NG * NOUT * sizeof(float), stream);
    k_readout<<<(NN * NOUT + 255) / 256, 256, 0, stream>>>(x, batch, ro_W, ro_b, out);
}

// Round 8
// 711.023 us; speedup vs baseline: 3.3172x; 3.3172x over previous
//
#include <hip/hip_runtime.h>

// Problem constants (match reference)
constexpr int NN   = 50000;          // nodes
constexpr int NE   = 800000;         // edges before self loops
constexpr int NHD  = 4;              // heads
constexpr int CC   = 32;             // channels per head
constexpr int HCC  = 128;            // NHD*CC
constexpr int NL   = 3;              // layers
constexpr int NG   = 128;            // graphs
constexpr int NOUT = 10;             // out channels
constexpr float BN_EPS = 1e-5f;

constexpr int XS = 133;              // LDS x-row stride
constexpr int YS = 33;               // LDS y-row stride

// fp32 -> bf16 (round-to-nearest-even), packed pair helpers
__device__ inline unsigned f2bf_pack(float a, float b) {
    unsigned ua = __float_as_uint(a); ua += 0x7FFFu + ((ua >> 16) & 1u);
    unsigned ub = __float_as_uint(b); ub += 0x7FFFu + ((ub >> 16) & 1u);
    return (ua >> 16) | (ub & 0xFFFF0000u);
}
__device__ inline float bf_lo(unsigned p) { return __uint_as_float(p << 16); }
__device__ inline float bf_hi(unsigned p) { return __uint_as_float(p & 0xFFFF0000u); }

// -------------------------------------- embed gather + BN stats for layer 0
__global__ __launch_bounds__(256) void k_embed_stats(const int* __restrict__ idx,
                                                     const float* __restrict__ embed,
                                                     float* __restrict__ x,
                                                     float* __restrict__ stats) {
    int i0 = blockIdx.x * 256 + threadIdx.x;
    int stride = gridDim.x * 256;                 // multiple of 128
    float s = 0.f, q = 0.f;
    for (int i = i0; i < NN * HCC; i += stride) {
        float v = embed[idx[i >> 7] * HCC + (i & 127)];
        x[i] = v; s += v; q += v * v;
    }
    __shared__ float ssum[256], ssq[256];
    ssum[threadIdx.x] = s; ssq[threadIdx.x] = q;
    __syncthreads();
    if (threadIdx.x < HCC) {
        atomicAdd(&stats[threadIdx.x],       ssum[threadIdx.x] + ssum[threadIdx.x + HCC]);
        atomicAdd(&stats[HCC + threadIdx.x], ssq[threadIdx.x]  + ssq[threadIdx.x + HCC]);
    }
}

// ------------------------------------------------------------ CSR build: degree
__global__ __launch_bounds__(256) void k_hist(const int* __restrict__ ei,
                                              int* __restrict__ deg) {
    int e = blockIdx.x * 256 + threadIdx.x;
    if (e >= NE) return;
    atomicAdd(&deg[ei[NE + e]], 1);
}

// chunked single-block exclusive scan
__global__ __launch_bounds__(1024) void k_scan(const int* __restrict__ deg,
                                               int* __restrict__ rowptr) {
    __shared__ int sh[1024];
    int tid = threadIdx.x;
    const int CH = (NN + 1023) / 1024;            // 49
    int st = tid * CH, en = min(st + CH, NN);
    int sum = 0;
    for (int i = st; i < en; i++) sum += deg[i];
    sh[tid] = sum;
    __syncthreads();
    for (int off = 1; off < 1024; off <<= 1) {
        int v = (tid >= off) ? sh[tid - off] : 0;
        __syncthreads();
        sh[tid] += v;
        __syncthreads();
    }
    int base = sh[tid] - sum;                     // exclusive prefix of chunk
    for (int i = st; i < en; i++) { rowptr[i] = base; base += deg[i]; }
}

// scatter edges by dst; only src needed per CSR slot (dst = owning node).
// Mutates rowptr: afterwards rowptr[d] == end(d).
__global__ __launch_bounds__(256) void k_scatter(const int* __restrict__ ei,
                                                 int* __restrict__ rowptr,
                                                 int* __restrict__ e_src) {
    int e = blockIdx.x * 256 + threadIdx.x;
    if (e >= NE) return;
    int d = ei[NE + e];
    int pos = atomicAdd(&rowptr[d], 1);
    e_src[pos] = ei[e];
}

// ---------- fused BNfin + BN-apply + Linear(128->32)+ReLU + GATw(32->128) + att
__global__ __launch_bounds__(256) void k_fused(const float* __restrict__ x,
                                               const float* __restrict__ stats,
                                               const float* __restrict__ gamma,
                                               const float* __restrict__ beta,
                                               const float* __restrict__ W1, // [32,128]
                                               const float* __restrict__ b1, // [32]
                                               const float* __restrict__ W2, // [128,32]
                                               const float* __restrict__ aS, // [4,32]
                                               const float* __restrict__ aD, // [4,32]
                                               unsigned* __restrict__ h,     // [N,64] packed
                                               float* __restrict__ asrc,     // [N,4]
                                               float* __restrict__ adst) {   // [N,4]
    __shared__ float xb[64 * XS];
    __shared__ float yt[64 * YS];
    __shared__ float w1[32 * 128];
    __shared__ float w2[128 * 32];
    __shared__ float attS[128], attD[128], ssl[256];
    int tid = threadIdx.x;
    int node0 = blockIdx.x * 64;
    int nNodes = min(64, NN - node0);

    for (int i = tid; i < 4096; i += 256) { w1[i] = W1[i]; w2[i] = W2[i]; }
    if (tid < 128) {
        attS[tid] = aS[tid]; attD[tid] = aD[tid];
        float mean = stats[tid] * (1.0f / NN);
        float var  = stats[HCC + tid] * (1.0f / NN) - mean * mean;
        float sc   = gamma[tid] * rsqrtf(var + BN_EPS);
        ssl[tid]       = sc;
        ssl[HCC + tid] = beta[tid] - mean * sc;
    }
    __syncthreads();   // ssl read cross-wave below

    for (int f4 = tid; f4 < nNodes * 32; f4 += 256) {
        int f = f4 * 4; int n = f >> 7; int c = f & 127;
        float4 xv = *(const float4*)(x + (size_t)(node0 + n) * HCC + c);
        float* dst = &xb[n * XS + c];
        dst[0] = xv.x * ssl[c]     + ssl[HCC + c];
        dst[1] = xv.y * ssl[c + 1] + ssl[HCC + c + 1];
        dst[2] = xv.z * ssl[c + 2] + ssl[HCC + c + 2];
        dst[3] = xv.w * ssl[c + 3] + ssl[HCC + c + 3];
    }
    __syncthreads();

    int lane = tid & 63, wv = tid >> 6;
    int n = lane;

    // ---- stage 1: y[n][j0..j0+7]
    {
        int j0 = wv * 8;
        float acc[8];
#pragma unroll
        for (int k = 0; k < 8; k++) acc[k] = b1[j0 + k];
        if (n < nNodes) {
            for (int cb = 0; cb < 128; cb += 4) {
                float xv0 = xb[n * XS + cb],     xv1 = xb[n * XS + cb + 1];
                float xv2 = xb[n * XS + cb + 2], xv3 = xb[n * XS + cb + 3];
#pragma unroll
                for (int k = 0; k < 8; k++) {
                    float4 w = *(const float4*)&w1[(j0 + k) * 128 + cb];
                    acc[k] += xv0 * w.x + xv1 * w.y + xv2 * w.z + xv3 * w.w;
                }
            }
#pragma unroll
            for (int k = 0; k < 8; k++) yt[n * YS + j0 + k] = fmaxf(acc[k], 0.f);
        }
    }
    __syncthreads();

    // ---- stage 2: h[n][k0..k0+31] (bf16), head hd = wv, + attention dots
    if (n < nNodes) {
        int k0 = wv * 32, hd = wv;
        float yreg[32];
#pragma unroll
        for (int j = 0; j < 32; j++) yreg[j] = yt[n * YS + j];
        float sa = 0.f, da = 0.f;
        unsigned* hrow = h + (size_t)(node0 + n) * 64;
        for (int kb = 0; kb < 32; kb += 8) {
            float acck[8];
#pragma unroll
            for (int kk = 0; kk < 8; kk++) acck[kk] = 0.f;
#pragma unroll
            for (int j = 0; j < 32; j += 4) {
#pragma unroll
                for (int kk = 0; kk < 8; kk++) {
                    float4 w = *(const float4*)&w2[(k0 + kb + kk) * 32 + j];
                    acck[kk] += yreg[j] * w.x + yreg[j + 1] * w.y +
                                yreg[j + 2] * w.z + yreg[j + 3] * w.w;
                }
            }
#pragma unroll
            for (int kk = 0; kk < 8; kk++) {
                sa += acck[kk] * attS[hd * 32 + kb + kk];
                da += acck[kk] * attD[hd * 32 + kb + kk];
            }
            uint4 pk;
            pk.x = f2bf_pack(acck[0], acck[1]);
            pk.y = f2bf_pack(acck[2], acck[3]);
            pk.z = f2bf_pack(acck[4], acck[5]);
            pk.w = f2bf_pack(acck[6], acck[7]);
            *(uint4*)(hrow + ((k0 + kb) >> 1)) = pk;
        }
        asrc[(node0 + n) * 4 + hd] = sa;
        adst[(node0 + n) * 4 + hd] = da;
    }
}

// -------- gather-aggregate v3: 16 lanes per edge (uint4 = full 256B bf16 row),
// 4 edges per wave-instruction, register accumulation, shfl_xor cross-group
// combine per node. Wave owns 4 consecutive dst nodes.
__global__ __launch_bounds__(256) void k_agg(const int* __restrict__ rowptr,
                                             const int* __restrict__ e_src,
                                             const float* __restrict__ asrc,
                                             const float* __restrict__ adst,
                                             const unsigned* __restrict__ h, // [N,64]
                                             const float* __restrict__ gat_b,
                                             float* __restrict__ xo,
                                             float* __restrict__ stats,
                                             int do_stats) {
    int tid = threadIdx.x, lane = tid & 63, wv = tid >> 6;
    int g  = lane >> 4;        // edge group 0..3
    int li = lane & 15;        // lane within group: channels 8li..8li+7
    int hd = li >> 2;          // head of this channel block
    int nodeBase = blockIdx.x * 16 + wv * 4;

    // bias for my 8 channels (all lanes load; only g==0 uses)
    float4 bA = *(const float4*)(gat_b + li * 8);
    float4 bB = *(const float4*)(gat_b + li * 8 + 4);

    float S[8], Q[8];
#pragma unroll
    for (int k = 0; k < 8; k++) { S[k] = 0.f; Q[k] = 0.f; }

    for (int nn = 0; nn < 4; nn++) {
        int d = nodeBase + nn;
        if (d >= NN) break;
        int begin = d ? rowptr[d - 1] : 0, end = rowptr[d];
        float adv = adst[d * 4 + hd];

        float acc[8];
#pragma unroll
        for (int k = 0; k < 8; k++) acc[k] = 0.f;
        float ws = 0.f;

        // self loop (group 0 weight only; row load is broadcast across groups)
        {
            uint4 hp = *(const uint4*)(h + (size_t)d * 64 + li * 4);
            float l = asrc[d * 4 + hd] + adv; l = l > 0.f ? l : 0.2f * l;
            float w = (g == 0) ? __expf(l) : 0.f;
            acc[0] += w * bf_lo(hp.x); acc[1] += w * bf_hi(hp.x);
            acc[2] += w * bf_lo(hp.y); acc[3] += w * bf_hi(hp.y);
            acc[4] += w * bf_lo(hp.z); acc[5] += w * bf_hi(hp.z);
            acc[6] += w * bf_lo(hp.w); acc[7] += w * bf_hi(hp.w);
            ws += w;
        }

        // 8 edges per iteration: 2 slots of 4 (2 gathers + 2 idx + 2 asrc in flight)
        for (int j = begin; j < end; j += 8) {
            int j0 = j + g, j1 = j + 4 + g;
            int jc0 = j0 < end ? j0 : end - 1;
            int jc1 = j1 < end ? j1 : end - 1;
            int s0 = e_src[jc0];
            int s1 = e_src[jc1];
            uint4 h0 = *(const uint4*)(h + (size_t)s0 * 64 + li * 4);
            uint4 h1 = *(const uint4*)(h + (size_t)s1 * 64 + li * 4);
            float a0 = asrc[s0 * 4 + hd];
            float a1 = asrc[s1 * 4 + hd];
            float l0 = a0 + adv; l0 = l0 > 0.f ? l0 : 0.2f * l0;
            float l1 = a1 + adv; l1 = l1 > 0.f ? l1 : 0.2f * l1;
            float w0 = (j0 < end) ? __expf(l0) : 0.f;
            float w1 = (j1 < end) ? __expf(l1) : 0.f;
            acc[0] += w0 * bf_lo(h0.x) + w1 * bf_lo(h1.x);
            acc[1] += w0 * bf_hi(h0.x) + w1 * bf_hi(h1.x);
            acc[2] += w0 * bf_lo(h0.y) + w1 * bf_lo(h1.y);
            acc[3] += w0 * bf_hi(h0.y) + w1 * bf_hi(h1.y);
            acc[4] += w0 * bf_lo(h0.z) + w1 * bf_lo(h1.z);
            acc[5] += w0 * bf_hi(h0.z) + w1 * bf_hi(h1.z);
            acc[6] += w0 * bf_lo(h0.w) + w1 * bf_lo(h1.w);
            acc[7] += w0 * bf_hi(h0.w) + w1 * bf_hi(h1.w);
            ws += w0 + w1;
        }

        // combine the 4 edge-groups (lanes L, L+16, L+32, L+48 hold same channels)
#pragma unroll
        for (int k = 0; k < 8; k++) {
            acc[k] += __shfl_xor(acc[k], 16);
            acc[k] += __shfl_xor(acc[k], 32);
        }
        ws += __shfl_xor(ws, 16);
        ws += __shfl_xor(ws, 32);

        if (g == 0) {
            float inv = 1.0f / (ws + 1e-16f);
            float o[8];
            o[0] = acc[0] * inv + bA.x; o[1] = acc[1] * inv + bA.y;
            o[2] = acc[2] * inv + bA.z; o[3] = acc[3] * inv + bA.w;
            o[4] = acc[4] * inv + bB.x; o[5] = acc[5] * inv + bB.y;
            o[6] = acc[6] * inv + bB.z; o[7] = acc[7] * inv + bB.w;
            float* orow = xo + (size_t)d * HCC + li * 8;
            *(float4*)orow       = make_float4(o[0], o[1], o[2], o[3]);
            *(float4*)(orow + 4) = make_float4(o[4], o[5], o[6], o[7]);
#pragma unroll
            for (int k = 0; k < 8; k++) { S[k] += o[k]; Q[k] += o[k] * o[k]; }
        }
    }

    if (!do_stats) return;
    __shared__ float redS[512], redQ[512];
    if (g == 0) {
#pragma unroll
        for (int k = 0; k < 8; k++) {
            redS[wv * 128 + li * 8 + k] = S[k];
            redQ[wv * 128 + li * 8 + k] = Q[k];
        }
    }
    __syncthreads();
    if (tid < 128) {
        float v = redS[tid] + redS[128 + tid] + redS[256 + tid] + redS[384 + tid];
        atomicAdd(&stats[tid], v);
    } else if (tid < 256) {
        int c = tid - 128;
        float v = redQ[c] + redQ[128 + c] + redQ[256 + c] + redQ[384 + c];
        atomicAdd(&stats[128 + c], v);
    }
}

// ------------------------------------------------------- readout + graph pool
__global__ __launch_bounds__(256) void k_readout(const float* __restrict__ x,
                                                 const int* __restrict__ batch,
                                                 const float* __restrict__ W,  // [10,128]
                                                 const float* __restrict__ bb, // [10]
                                                 float* __restrict__ out) {    // [128,10]
    int i = blockIdx.x * 256 + threadIdx.x;
    if (i >= NN * NOUT) return;
    int n = i / NOUT, j = i - n * NOUT;
    const float* xr = x + (size_t)n * HCC;
    const float* wr = W + j * HCC;
    float acc = bb[j];
#pragma unroll
    for (int c = 0; c < HCC; c += 4) {
        float4 xv = *(const float4*)(xr + c);
        float4 wv = *(const float4*)(wr + c);
        acc += xv.x * wv.x + xv.y * wv.y + xv.z * wv.z + xv.w * wv.w;
    }
    atomicAdd(&out[batch[n] * NOUT + j], acc);
}

extern "C" void kernel_launch(void* const* d_in, const int* in_sizes, int n_in,
                              void* d_out, int out_size, void* d_ws, size_t ws_size,
                              hipStream_t stream) {
    const int*   x_idx = (const int*)d_in[0];
    const int*   ei    = (const int*)d_in[1];
    const int*   batch = (const int*)d_in[2];
    const float* embed = (const float*)d_in[3];
    const float* bn_g  = (const float*)d_in[4];
    const float* bn_b  = (const float*)d_in[5];
    const float* lin_W = (const float*)d_in[6];
    const float* lin_b = (const float*)d_in[7];
    const float* gat_W = (const float*)d_in[8];
    const float* att_s = (const float*)d_in[9];
    const float* att_d = (const float*)d_in[10];
    const float* gat_b = (const float*)d_in[11];
    const float* ro_W  = (const float*)d_in[12];
    const float* ro_b  = (const float*)d_in[13];
    float* out = (float*)d_out;

    // workspace layout
    float*    x     = (float*)d_ws;                        // [N,128] fp32
    unsigned* h     = (unsigned*)(x + (size_t)NN * HCC);   // [N,64] packed bf16
    float*    asrc  = (float*)(h + (size_t)NN * 64);       // [N,4]
    float*    adst  = asrc + (size_t)NN * NHD;             // [N,4]
    float*    stats = adst + (size_t)NN * NHD;             // [4][256]
    int*      deg    = (int*)(stats + 4 * 2 * HCC);        // [N]
    int*      rowptr = deg + NN;                           // [N]
    int*      e_src  = rowptr + NN;                        // [E]

    hipMemsetAsync(stats, 0, 4 * 2 * HCC * sizeof(float), stream);
    hipMemsetAsync(deg, 0, NN * sizeof(int), stream);

    k_embed_stats<<<512, 256, 0, stream>>>(x_idx, embed, x, stats);

    // CSR build (graph is static across layers)
    k_hist<<<(NE + 255) / 256, 256, 0, stream>>>(ei, deg);
    k_scan<<<1, 1024, 0, stream>>>(deg, rowptr);
    k_scatter<<<(NE + 255) / 256, 256, 0, stream>>>(ei, rowptr, e_src);

    for (int l = 0; l < NL; ++l) {
        k_fused<<<(NN + 63) / 64, 256, 0, stream>>>(x, stats + l * 2 * HCC,
                                                    bn_g + l * HCC, bn_b + l * HCC,
                                                    lin_W + l * CC * HCC, lin_b + l * CC,
                                                    gat_W + l * HCC * CC,
                                                    att_s + l * NHD * CC,
                                                    att_d + l * NHD * CC,
                                                    h, asrc, adst);
        k_agg<<<(NN + 15) / 16, 256, 0, stream>>>(rowptr, e_src, asrc, adst, h,
                                                  gat_b + l * HCC, x,
                                                  stats + (l + 1) * 2 * HCC,
                                                  (l < NL - 1) ? 1 : 0);
    }

    hipMemsetAsync(out, 0, NG * NOUT * sizeof(float), stream);
    k_readout<<<(NN * NOUT + 255) / 256, 256, 0, stream>>>(x, batch, ro_W, ro_b, out);
}